// Round 1
// baseline (377.797 us; speedup 1.0000x reference)
//
#include <hip/hip_runtime.h>
#include <math.h>

#define C_DIM 256
#define HW 16384           // 128*128
#define HW4 4096           // HW / 4

typedef float vfloat4 __attribute__((ext_vector_type(4)));

// Kernel 1: fused global avg+max pool per (b,c) plane.
// grid = B*C = 4096 blocks, 256 threads. Each plane is 16384 contiguous floats.
// R1: PLAIN cached loads (nontemporal removed). The measured 6.3 TB/s read
// ceiling (m13) is with cached loads; nt bypasses L2 request aggregation and
// forfeits any Infinity-Cache residency of the exactly-LLC-sized 256 MiB input.
// Single-touch stream => nothing to protect with nt anyway.
__global__ __launch_bounds__(256) void pool_kernel(const float* __restrict__ x,
                                                   float* __restrict__ avg,
                                                   float* __restrict__ mx) {
    const int plane = blockIdx.x;  // b*C + c
    const vfloat4* __restrict__ p =
        reinterpret_cast<const vfloat4*>(x + (size_t)plane * HW);

    float s = 0.0f;
    float m = -INFINITY;
#pragma unroll
    for (int i = 0; i < HW4 / 256; ++i) {   // 16 independent float4 per thread
        const vfloat4 v = p[threadIdx.x + i * 256];
        s += (v.x + v.y) + (v.z + v.w);
        m = fmaxf(m, fmaxf(fmaxf(v.x, v.y), fmaxf(v.z, v.w)));
    }

    // wave-64 shuffle reduction
#pragma unroll
    for (int off = 32; off > 0; off >>= 1) {
        s += __shfl_down(s, off, 64);
        m = fmaxf(m, __shfl_down(m, off, 64));
    }

    __shared__ float ss[4];
    __shared__ float sm[4];
    const int lane = threadIdx.x & 63;
    const int wave = threadIdx.x >> 6;
    if (lane == 0) { ss[wave] = s; sm[wave] = m; }
    __syncthreads();
    if (threadIdx.x == 0) {
        float S = (ss[0] + ss[1]) + (ss[2] + ss[3]);
        float M = fmaxf(fmaxf(sm[0], sm[1]), fmaxf(sm[2], sm[3]));
        avg[plane] = S * (1.0f / (float)HW);
        mx[plane]  = M;
    }
}

// Kernel 2: per-batch shared MLP on both pooled vectors + sigmoid.
// grid = B = 16 blocks, 256 threads (one per output channel o).
// R1: vfloat4 LDS broadcast reads, unroll-16 weight loops (16 loads in
// flight vs 4), and w2-row prefetch (16 quads) issued before the first
// barrier so its latency hides under layer-1 compute.
__global__ __launch_bounds__(256) void mlp_kernel(const float* __restrict__ w1,
                                                  const float* __restrict__ w2,
                                                  const float* __restrict__ avg,
                                                  const float* __restrict__ mx,
                                                  float* __restrict__ out) {
    const int b = blockIdx.x;
    const int o = threadIdx.x;

    __shared__ __align__(16) float sa[C_DIM];   // avg vector for this batch
    __shared__ __align__(16) float sx[C_DIM];   // max vector
    __shared__ __align__(16) float ha[C_DIM];   // relu(w1@avg)
    __shared__ __align__(16) float hx[C_DIM];   // relu(w1@max)

    sa[o] = avg[b * C_DIM + o];
    sx[o] = mx[b * C_DIM + o];

    const vfloat4* __restrict__ w1r =
        reinterpret_cast<const vfloat4*>(w1 + (size_t)o * C_DIM);
    const vfloat4* __restrict__ w2r =
        reinterpret_cast<const vfloat4*>(w2 + (size_t)o * C_DIM);

    // Prefetch first 16 quads (64 floats) of this thread's w2 row. These are
    // independent of layer-1; issuing them now overlaps their memory latency
    // with the barrier + layer-1 FMA loop.
    vfloat4 pw[16];
#pragma unroll
    for (int i = 0; i < 16; ++i) pw[i] = w2r[i];

    __syncthreads();

    const vfloat4* sa4 = reinterpret_cast<const vfloat4*>(sa);
    const vfloat4* sx4 = reinterpret_cast<const vfloat4*>(sx);

    // layer 1: thread o = row o of w1; same weight feeds both avg and max dots.
    {
        float da = 0.0f, dm = 0.0f;
#pragma unroll 16
        for (int c4 = 0; c4 < C_DIM / 4; ++c4) {
            const vfloat4 w = w1r[c4];
            const vfloat4 a = sa4[c4];   // LDS broadcast (all lanes same addr)
            const vfloat4 xm = sx4[c4];
            da = fmaf(w.x, a.x, da);  dm = fmaf(w.x, xm.x, dm);
            da = fmaf(w.y, a.y, da);  dm = fmaf(w.y, xm.y, dm);
            da = fmaf(w.z, a.z, da);  dm = fmaf(w.z, xm.z, dm);
            da = fmaf(w.w, a.w, da);  dm = fmaf(w.w, xm.w, dm);
        }
        ha[o] = fmaxf(da, 0.0f);
        hx[o] = fmaxf(dm, 0.0f);
    }
    __syncthreads();

    // layer 2 + sigmoid
    {
        const vfloat4* ha4 = reinterpret_cast<const vfloat4*>(ha);
        const vfloat4* hx4 = reinterpret_cast<const vfloat4*>(hx);
        float oa = 0.0f, om = 0.0f;
        // first 16 quads come from the prefetch registers
#pragma unroll
        for (int i = 0; i < 16; ++i) {
            const vfloat4 w = pw[i];
            const vfloat4 a = ha4[i];
            const vfloat4 xm = hx4[i];
            oa = fmaf(w.x, a.x, oa);  om = fmaf(w.x, xm.x, om);
            oa = fmaf(w.y, a.y, oa);  om = fmaf(w.y, xm.y, om);
            oa = fmaf(w.z, a.z, oa);  om = fmaf(w.z, xm.z, om);
            oa = fmaf(w.w, a.w, oa);  om = fmaf(w.w, xm.w, om);
        }
#pragma unroll 16
        for (int c4 = 16; c4 < C_DIM / 4; ++c4) {
            const vfloat4 w = w2r[c4];
            const vfloat4 a = ha4[c4];
            const vfloat4 xm = hx4[c4];
            oa = fmaf(w.x, a.x, oa);  om = fmaf(w.x, xm.x, om);
            oa = fmaf(w.y, a.y, oa);  om = fmaf(w.y, xm.y, om);
            oa = fmaf(w.z, a.z, oa);  om = fmaf(w.z, xm.z, om);
            oa = fmaf(w.w, a.w, oa);  om = fmaf(w.w, xm.w, om);
        }
        const float v = oa + om;
        out[b * C_DIM + o] = 1.0f / (1.0f + expf(-v));
    }
}

extern "C" void kernel_launch(void* const* d_in, const int* in_sizes, int n_in,
                              void* d_out, int out_size, void* d_ws, size_t ws_size,
                              hipStream_t stream) {
    const float* x  = (const float*)d_in[0];   // [16,256,128,128]
    const float* w1 = (const float*)d_in[1];   // [256,256]
    const float* w2 = (const float*)d_in[2];   // [256,256]
    float* out = (float*)d_out;                // [16,256] (== [16,256,1,1] flat)

    float* avg = (float*)d_ws;                 // 4096 floats
    float* mx  = avg + 16 * C_DIM;             // 4096 floats

    pool_kernel<<<16 * C_DIM, 256, 0, stream>>>(x, avg, mx);
    mlp_kernel<<<16, 256, 0, stream>>>(w1, w2, avg, mx, out);
}

// Round 2
// 354.146 us; speedup vs baseline: 1.0668x; 1.0668x over previous
//
#include <hip/hip_runtime.h>
#include <math.h>

#define C_DIM 256
#define HW 16384           // 128*128
#define HW4 4096           // HW / 4

typedef float vfloat4 __attribute__((ext_vector_type(4)));

// Kernel 1: fused global avg+max pool per (b,c) plane.
// grid = B*C = 4096 blocks, 256 threads. Each plane is 16384 contiguous floats.
// R2: nontemporal loads RESTORED. Measured A/B (R0=353.9 w/ nt, R1=377.8
// cached): nt is worth ~24 us on this 268 MB single-touch stream. The 1 GiB
// poison fills between iterations flush L2/LLC regardless, so cached loads
// buy no reuse and pay L2 allocate/evict churn; nt streams past it.
__global__ __launch_bounds__(256) void pool_kernel(const float* __restrict__ x,
                                                   float* __restrict__ avg,
                                                   float* __restrict__ mx) {
    const int plane = blockIdx.x;  // b*C + c
    const vfloat4* p = reinterpret_cast<const vfloat4*>(x + (size_t)plane * HW);

    float s = 0.0f;
    float m = -INFINITY;
#pragma unroll
    for (int i = 0; i < HW4 / 256; ++i) {   // 16 float4 per thread, independent
        vfloat4 v = __builtin_nontemporal_load(&p[threadIdx.x + i * 256]);
        s += (v.x + v.y) + (v.z + v.w);
        m = fmaxf(m, fmaxf(fmaxf(v.x, v.y), fmaxf(v.z, v.w)));
    }

    // wave-64 shuffle reduction
#pragma unroll
    for (int off = 32; off > 0; off >>= 1) {
        s += __shfl_down(s, off, 64);
        m = fmaxf(m, __shfl_down(m, off, 64));
    }

    __shared__ float ss[4];
    __shared__ float sm[4];
    const int lane = threadIdx.x & 63;
    const int wave = threadIdx.x >> 6;
    if (lane == 0) { ss[wave] = s; sm[wave] = m; }
    __syncthreads();
    if (threadIdx.x == 0) {
        float S = (ss[0] + ss[1]) + (ss[2] + ss[3]);
        float M = fmaxf(fmaxf(sm[0], sm[1]), fmaxf(sm[2], sm[3]));
        avg[plane] = S * (1.0f / (float)HW);
        mx[plane]  = M;
    }
}

// Kernel 2: per-batch shared MLP on both pooled vectors + sigmoid.
// grid = B = 16 blocks, 256 threads (one per output channel o).
// Kept from R1: vfloat4 LDS broadcast reads, unroll-16 weight loops (16
// loads in flight vs 4), and w2-row prefetch (16 quads) issued before the
// first barrier so its latency hides under layer-1 compute.
__global__ __launch_bounds__(256) void mlp_kernel(const float* __restrict__ w1,
                                                  const float* __restrict__ w2,
                                                  const float* __restrict__ avg,
                                                  const float* __restrict__ mx,
                                                  float* __restrict__ out) {
    const int b = blockIdx.x;
    const int o = threadIdx.x;

    __shared__ __align__(16) float sa[C_DIM];   // avg vector for this batch
    __shared__ __align__(16) float sx[C_DIM];   // max vector
    __shared__ __align__(16) float ha[C_DIM];   // relu(w1@avg)
    __shared__ __align__(16) float hx[C_DIM];   // relu(w1@max)

    sa[o] = avg[b * C_DIM + o];
    sx[o] = mx[b * C_DIM + o];

    const vfloat4* __restrict__ w1r =
        reinterpret_cast<const vfloat4*>(w1 + (size_t)o * C_DIM);
    const vfloat4* __restrict__ w2r =
        reinterpret_cast<const vfloat4*>(w2 + (size_t)o * C_DIM);

    // Prefetch first 16 quads (64 floats) of this thread's w2 row. These are
    // independent of layer-1; issuing them now overlaps their memory latency
    // with the barrier + layer-1 FMA loop.
    vfloat4 pw[16];
#pragma unroll
    for (int i = 0; i < 16; ++i) pw[i] = w2r[i];

    __syncthreads();

    const vfloat4* sa4 = reinterpret_cast<const vfloat4*>(sa);
    const vfloat4* sx4 = reinterpret_cast<const vfloat4*>(sx);

    // layer 1: thread o = row o of w1; same weight feeds both avg and max dots.
    {
        float da = 0.0f, dm = 0.0f;
#pragma unroll 16
        for (int c4 = 0; c4 < C_DIM / 4; ++c4) {
            const vfloat4 w = w1r[c4];
            const vfloat4 a = sa4[c4];   // LDS broadcast (all lanes same addr)
            const vfloat4 xm = sx4[c4];
            da = fmaf(w.x, a.x, da);  dm = fmaf(w.x, xm.x, dm);
            da = fmaf(w.y, a.y, da);  dm = fmaf(w.y, xm.y, dm);
            da = fmaf(w.z, a.z, da);  dm = fmaf(w.z, xm.z, dm);
            da = fmaf(w.w, a.w, da);  dm = fmaf(w.w, xm.w, dm);
        }
        ha[o] = fmaxf(da, 0.0f);
        hx[o] = fmaxf(dm, 0.0f);
    }
    __syncthreads();

    // layer 2 + sigmoid
    {
        const vfloat4* ha4 = reinterpret_cast<const vfloat4*>(ha);
        const vfloat4* hx4 = reinterpret_cast<const vfloat4*>(hx);
        float oa = 0.0f, om = 0.0f;
        // first 16 quads come from the prefetch registers
#pragma unroll
        for (int i = 0; i < 16; ++i) {
            const vfloat4 w = pw[i];
            const vfloat4 a = ha4[i];
            const vfloat4 xm = hx4[i];
            oa = fmaf(w.x, a.x, oa);  om = fmaf(w.x, xm.x, om);
            oa = fmaf(w.y, a.y, oa);  om = fmaf(w.y, xm.y, om);
            oa = fmaf(w.z, a.z, oa);  om = fmaf(w.z, xm.z, om);
            oa = fmaf(w.w, a.w, oa);  om = fmaf(w.w, xm.w, om);
        }
#pragma unroll 16
        for (int c4 = 16; c4 < C_DIM / 4; ++c4) {
            const vfloat4 w = w2r[c4];
            const vfloat4 a = ha4[c4];
            const vfloat4 xm = hx4[c4];
            oa = fmaf(w.x, a.x, oa);  om = fmaf(w.x, xm.x, om);
            oa = fmaf(w.y, a.y, oa);  om = fmaf(w.y, xm.y, om);
            oa = fmaf(w.z, a.z, oa);  om = fmaf(w.z, xm.z, om);
            oa = fmaf(w.w, a.w, oa);  om = fmaf(w.w, xm.w, om);
        }
        const float v = oa + om;
        out[b * C_DIM + o] = 1.0f / (1.0f + expf(-v));
    }
}

extern "C" void kernel_launch(void* const* d_in, const int* in_sizes, int n_in,
                              void* d_out, int out_size, void* d_ws, size_t ws_size,
                              hipStream_t stream) {
    const float* x  = (const float*)d_in[0];   // [16,256,128,128]
    const float* w1 = (const float*)d_in[1];   // [256,256]
    const float* w2 = (const float*)d_in[2];   // [256,256]
    float* out = (float*)d_out;                // [16,256] (== [16,256,1,1] flat)

    float* avg = (float*)d_ws;                 // 4096 floats
    float* mx  = avg + 16 * C_DIM;             // 4096 floats

    pool_kernel<<<16 * C_DIM, 256, 0, stream>>>(x, avg, mx);
    mlp_kernel<<<16, 256, 0, stream>>>(w1, w2, avg, mx, out);
}